// Round 2
// baseline (4024.388 us; speedup 1.0000x reference)
//
#include <hip/hip_runtime.h>
#include <stdint.h>
#include <math.h>

#define NB 4
#define CIN 512
#define CMID 512
#define HH 50
#define WW 50
#define NPIX 2500
#define AA 9
#define RR 22500
#define PB 6000
#define PA 300
#define LOCCH 36
#define SCORECH 18
#define HEADCH 54
#define CI_T 16

typedef unsigned long long u64;

// ---------------- anchors (f64 math, f32 out — ref casts to f32) ----------------
__global__ void anchor_kernel(float* __restrict__ out4) {
    int r = blockIdx.x * 256 + threadIdx.x;
    if (r >= RR) return;
    int a = r % AA;
    int p = r / AA;
    int gy = p / WW, gx = p % WW;
    int ri = a / 3, si = a % 3;
    const double ratios[3] = {0.5, 1.0, 2.0};
    const double scales[3] = {8.0, 16.0, 32.0};
    double h = 16.0 * sqrt(ratios[ri]) * scales[si];
    double w = 16.0 * sqrt(1.0 / ratios[ri]) * scales[si];
    float by1 = (float)(8.0 - h * 0.5);
    float bx1 = (float)(8.0 - w * 0.5);
    float by2 = (float)(8.0 + h * 0.5);
    float bx2 = (float)(8.0 + w * 0.5);
    float sy = (float)(gy * 16), sx = (float)(gx * 16);
    float* o = out4 + (size_t)r * 4;
    o[0] = by1 + sy; o[1] = bx1 + sx; o[2] = by2 + sy; o[3] = bx2 + sx;
}

// ---------------- 3x3 conv + bias + relu, f64 accumulate ----------------
// grid (49, 8), block 256, one batch per launch. 64 couts x 8x8 px, 4x4/thread.
__global__ __launch_bounds__(256) void conv3_kernel_f64(
    const float* __restrict__ x, const float* __restrict__ w1,
    const float* __restrict__ b1, double* __restrict__ inter, int n) {
    __shared__ float xs[CI_T][10][10];
    __shared__ float wsm[CI_T * 9][65];

    int tile = blockIdx.x;
    int ty = tile / 7, tx = tile % 7;
    int co0 = blockIdx.y * 64;
    int tid = threadIdx.x;
    int tm = tid % 16;
    int tp = tid / 16;
    int pyt = tp >> 1;
    int px0 = (tp & 1) * 4;
    int gy0 = ty * 8, gx0 = tx * 8;

    double acc[4][4] = {};

    for (int cc = 0; cc < CIN; cc += CI_T) {
        for (int e = tid; e < CI_T * 100; e += 256) {
            int col = e % 10;
            int row = (e / 10) % 10;
            int ci = e / 100;
            int gy = gy0 - 1 + row, gx = gx0 - 1 + col;
            float v = 0.f;
            if (gy >= 0 && gy < HH && gx >= 0 && gx < WW)
                v = x[(((size_t)n * CIN + cc + ci) * HH + gy) * WW + gx];
            xs[ci][row][col] = v;
        }
        for (int e = tid; e < 64 * 144; e += 256) {
            int m = e / 144;
            int q = e % 144;
            wsm[q][m] = w1[((size_t)(co0 + m) * CIN + cc) * 9 + q];
        }
        __syncthreads();

        for (int ci = 0; ci < CI_T; ++ci) {
            #pragma unroll
            for (int ky = 0; ky < 3; ++ky) {
                double xa[6];
                #pragma unroll
                for (int j = 0; j < 6; ++j) xa[j] = (double)xs[ci][pyt + ky][px0 + j];
                #pragma unroll
                for (int kx = 0; kx < 3; ++kx) {
                    const float* wr = &wsm[ci * 9 + ky * 3 + kx][tm * 4];
                    double w0 = (double)wr[0], w1v = (double)wr[1];
                    double w2 = (double)wr[2], w3 = (double)wr[3];
                    #pragma unroll
                    for (int j = 0; j < 4; ++j) {
                        double xv = xa[kx + j];
                        acc[0][j] = fma(w0, xv, acc[0][j]);
                        acc[1][j] = fma(w1v, xv, acc[1][j]);
                        acc[2][j] = fma(w2, xv, acc[2][j]);
                        acc[3][j] = fma(w3, xv, acc[3][j]);
                    }
                }
            }
        }
        __syncthreads();
    }

    #pragma unroll
    for (int i = 0; i < 4; ++i) {
        int co = co0 + tm * 4 + i;
        double bias = (double)b1[co];
        #pragma unroll
        for (int j = 0; j < 4; ++j) {
            int gy = gy0 + pyt, gx = gx0 + px0 + j;
            if (gy < HH && gx < WW) {
                double v = acc[i][j] + bias;
                v = fmax(v, 0.0);
                inter[(size_t)co * NPIX + gy * WW + gx] = v;
            }
        }
    }
}

// ---------------- 1x1 heads, f64 ----------------
#define HP 128
#define HCI 32
__global__ __launch_bounds__(256) void heads_kernel_f64(
    const double* __restrict__ inter,
    const float* __restrict__ w_loc, const float* __restrict__ b_loc,
    const float* __restrict__ w_score, const float* __restrict__ b_score,
    double* __restrict__ loc64, double* __restrict__ score64,
    float* __restrict__ out_loc, float* __restrict__ out_score, int n) {
    __shared__ double xsh[HCI][HP];
    __shared__ double wsh[HEADCH][HCI];
    int p0 = blockIdx.x * HP;
    int tid = threadIdx.x;
    int pl = tid % HP;
    int g = tid / HP;
    double acc[27] = {};

    for (int cc = 0; cc < CMID; cc += HCI) {
        for (int e = tid; e < HCI * HP; e += 256) {
            int p = e % HP;
            int ci = e / HP;
            int gp = p0 + p;
            xsh[ci][p] = (gp < NPIX) ? inter[(size_t)(cc + ci) * NPIX + gp] : 0.0;
        }
        for (int e = tid; e < HEADCH * HCI; e += 256) {
            int ci = e % HCI;
            int u = e / HCI;
            float wv = (u < LOCCH) ? w_loc[(size_t)u * CMID + cc + ci]
                                   : w_score[(size_t)(u - LOCCH) * CMID + cc + ci];
            wsh[u][ci] = (double)wv;
        }
        __syncthreads();
        for (int ci = 0; ci < HCI; ++ci) {
            double xv = xsh[ci][pl];
            #pragma unroll
            for (int o = 0; o < 27; ++o)
                acc[o] = fma(wsh[g * 27 + o][ci], xv, acc[o]);
        }
        __syncthreads();
    }

    int gp = p0 + pl;
    if (gp < NPIX) {
        #pragma unroll
        for (int o = 0; o < 27; ++o) {
            int u = g * 27 + o;
            if (u < LOCCH) {
                double v = acc[o] + (double)b_loc[u];
                loc64[(size_t)n * RR * 4 + (size_t)gp * 36 + u] = v;
                out_loc[(size_t)n * RR * 4 + (size_t)gp * 36 + u] = (float)v;
            } else {
                int us = u - LOCCH;
                double v = acc[o] + (double)b_score[us];
                score64[(size_t)n * RR * 2 + (size_t)gp * 18 + us] = v;
                out_score[(size_t)n * RR * 2 + (size_t)gp * 18 + us] = (float)v;
            }
        }
    }
}

// ---------------- fg = softmax(score)[...,1], f64 ----------------
__global__ void fg_kernel_f64(const double* __restrict__ score64, double* __restrict__ fg) {
    int idx = blockIdx.x * 256 + threadIdx.x;
    if (idx >= NB * RR) return;
    double s0 = score64[(size_t)idx * 2];
    double s1 = score64[(size_t)idx * 2 + 1];
    double m = fmax(s0, s1);
    double e0 = exp(s0 - m), e1 = exp(s1 - m);
    fg[idx] = e1 / (e0 + e1);
}

// ---------------- decode boxes + keys, f64 ----------------
// key = 49-bit monotone transform of f64 score | 15-bit (32767-r) index tiebreak
__global__ void box_kernel_f64(const double* __restrict__ loc64, const float* __restrict__ anchor,
                               const double* __restrict__ fg,
                               const int* __restrict__ imh_p, const int* __restrict__ imw_p,
                               double* __restrict__ boxes, u64* __restrict__ keys) {
    int idx = blockIdx.x * 256 + threadIdx.x;
    if (idx >= NB * RR) return;
    int r = idx % RR;
    const double* l = loc64 + (size_t)idx * 4;
    double a0 = (double)anchor[(size_t)r * 4 + 0];
    double a1 = (double)anchor[(size_t)r * 4 + 1];
    double a2 = (double)anchor[(size_t)r * 4 + 2];
    double a3 = (double)anchor[(size_t)r * 4 + 3];
    double ah = a2 - a0, aw = a3 - a1;
    double acy = a0 + 0.5 * ah, acx = a1 + 0.5 * aw;
    double cy = l[0] * ah + acy, cx = l[1] * aw + acx;
    double h = exp(l[2]) * ah, w = exp(l[3]) * aw;
    double imh = (double)imh_p[0], imw = (double)imw_p[0];
    double y1 = fmin(fmax(cy - 0.5 * h, 0.0), imh);
    double x1 = fmin(fmax(cx - 0.5 * w, 0.0), imw);
    double y2 = fmin(fmax(cy + 0.5 * h, 0.0), imh);
    double x2 = fmin(fmax(cx + 0.5 * w, 0.0), imw);
    bool valid = ((y2 - y1) >= 16.0) && ((x2 - x1) >= 16.0);
    double* b = boxes + (size_t)idx * 4;
    b[0] = y1; b[1] = x1; b[2] = y2; b[3] = x2;
    double sc = valid ? fg[idx] : -__builtin_inf();
    u64 bits = (u64)__double_as_longlong(sc);
    u64 t = (bits >> 63) ? ~bits : (bits | 0x8000000000000000ull);
    keys[idx] = (t & 0xFFFFFFFFFFFF8000ull) | (u64)(32767 - r);
}

// ---------------- top-6000 select + full sort (per batch) ----------------
__global__ __launch_bounds__(1024) void select_kernel(
    const u64* __restrict__ keys, const double* __restrict__ boxes,
    double* __restrict__ sbox, int* __restrict__ sval) {
    __shared__ unsigned int hist[256];
    __shared__ u64 cand[8192];
    __shared__ unsigned int s_sel, s_base, s_cnt;
    int n = blockIdx.x;
    int tid = threadIdx.x;
    const u64* k = keys + (size_t)n * RR;

    // 3-round radix on key bits [63:40] to find the 24-bit prefix at rank PB
    u64 prefix = 0;
    unsigned int base = 0;
    for (int round = 0; round < 3; ++round) {
        if (tid < 256) hist[tid] = 0;
        __syncthreads();
        int shift_match = 64 - 8 * round;   // 64, 56, 48
        int shift_bin = 56 - 8 * round;     // 56, 48, 40
        for (int r = tid; r < RR; r += 1024) {
            u64 kv = k[r];
            bool match = (round == 0) || ((kv >> shift_match) == prefix);
            if (match) atomicAdd(&hist[(unsigned int)((kv >> shift_bin) & 0xFF)], 1u);
        }
        __syncthreads();
        if (tid == 0) {
            unsigned int c = base;
            int sel = 0;
            for (int v = 255; v >= 0; --v) {
                if (c + hist[v] >= PB) { sel = v; break; }
                c += hist[v];
            }
            s_sel = (unsigned int)sel;
            s_base = c;
        }
        __syncthreads();
        prefix = (prefix << 8) | (u64)s_sel;
        base = s_base;
        __syncthreads();
    }

    if (tid == 0) s_cnt = 0;
    __syncthreads();
    for (int r = tid; r < RR; r += 1024) {
        u64 kv = k[r];
        if ((kv >> 40) >= prefix) {
            unsigned int pos = atomicAdd(&s_cnt, 1u);
            if (pos < 8192u) cand[pos] = kv;
        }
    }
    __syncthreads();
    unsigned int cnt = s_cnt;
    if (cnt > 8192u) cnt = 8192u;
    for (unsigned int i = cnt + tid; i < 8192u; i += 1024u) cand[i] = 0ull;
    __syncthreads();

    // bitonic sort descending
    for (unsigned int kk = 2; kk <= 8192; kk <<= 1) {
        for (unsigned int j = kk >> 1; j > 0; j >>= 1) {
            for (unsigned int t = tid; t < 4096; t += 1024) {
                unsigned int i = ((t & ~(j - 1)) << 1) | (t & (j - 1));
                unsigned int l = i | j;
                u64 a = cand[i], b = cand[l];
                bool desc = ((i & kk) == 0);
                if ((a < b) == desc) { cand[i] = b; cand[l] = a; }
            }
            __syncthreads();
        }
    }

    for (int s = tid; s < PB; s += 1024) {
        u64 kv = cand[s];
        int valid = (int)(kv >> 63);
        double b0 = 0.0, b1 = 0.0, b2 = 0.0, b3 = 0.0;
        if (valid) {
            int r = 32767 - (int)(kv & 0x7FFFull);
            const double* bp = boxes + ((size_t)n * RR + r) * 4;
            b0 = bp[0]; b1 = bp[1]; b2 = bp[2]; b3 = bp[3];
        }
        double* sp = sbox + ((size_t)n * PB + s) * 4;
        sp[0] = b0; sp[1] = b1; sp[2] = b2; sp[3] = b3;
        sval[n * PB + s] = valid;
    }
}

// ---------------- greedy NMS (f64 IoU), early-exit at 300 kept ----------------
__global__ __launch_bounds__(1024) void nms_kernel_f64(
    const double* __restrict__ sbox, const int* __restrict__ sval,
    float* __restrict__ rois, float* __restrict__ rind) {
    __shared__ unsigned int keepw[188];
    __shared__ double bi[4];
    int n = blockIdx.x;
    int tid = threadIdx.x;

    double by1[6], bx1[6], by2[6], bx2[6];
    bool kp[6];
    if (tid < 188) keepw[tid] = 0u;
    __syncthreads();
    #pragma unroll
    for (int c = 0; c < 6; ++c) {
        int j = tid + c * 1024;
        bool v = false;
        double a0 = 0, a1 = 0, a2 = 0, a3 = 0;
        if (j < PB) {
            const double* bp = sbox + ((size_t)n * PB + j) * 4;
            a0 = bp[0]; a1 = bp[1]; a2 = bp[2]; a3 = bp[3];
            v = sval[n * PB + j] != 0;
        }
        by1[c] = a0; bx1[c] = a1; by2[c] = a2; bx2[c] = a3;
        kp[c] = v;
        if (v) atomicOr(&keepw[j >> 5], 1u << (j & 31));
    }
    __syncthreads();

    int kc = 0;
    for (int i = 0; i < PB; ++i) {
        bool ki = (keepw[i >> 5] >> (i & 31)) & 1u;
        if (!ki) continue;
        int owner = i & 1023;
        int slot = i >> 10;
        if (tid == owner) {
            float* rp = rois + ((size_t)n * PA + kc) * 4;
            rp[0] = (float)by1[slot]; rp[1] = (float)bx1[slot];
            rp[2] = (float)by2[slot]; rp[3] = (float)bx2[slot];
            bi[0] = by1[slot]; bi[1] = bx1[slot]; bi[2] = by2[slot]; bi[3] = bx2[slot];
        }
        ++kc;
        if (kc >= PA) break;
        __syncthreads();
        double yi1 = bi[0], xi1 = bi[1], yi2 = bi[2], xi2 = bi[3];
        double ai = (yi2 - yi1) * (xi2 - xi1);
        #pragma unroll
        for (int c = 0; c < 6; ++c) {
            int j = tid + c * 1024;
            if (j > i && kp[c]) {
                double ty = fmax(yi1, by1[c]);
                double tx = fmax(xi1, bx1[c]);
                double byy = fmin(yi2, by2[c]);
                double bxx = fmin(xi2, bx2[c]);
                double ih = fmax(byy - ty, 0.0);
                double iw = fmax(bxx - tx, 0.0);
                double inter = ih * iw;
                double aj = (by2[c] - by1[c]) * (bx2[c] - bx1[c]);
                double iou = inter / (ai + aj - inter + 1e-9);
                if (iou > 0.7) {
                    kp[c] = false;
                    atomicAnd(&keepw[j >> 5], ~(1u << (j & 31)));
                }
            }
        }
        __syncthreads();
    }
    __syncthreads();

    for (int p = kc + tid; p < PA; p += 1024) {
        float* rp = rois + ((size_t)n * PA + p) * 4;
        rp[0] = 0.f; rp[1] = 0.f; rp[2] = 0.f; rp[3] = 0.f;
    }
    for (int p = tid; p < PA; p += 1024)
        rind[n * PA + p] = (float)n;
}

// ---------------- launch ----------------
extern "C" void kernel_launch(void* const* d_in, const int* in_sizes, int n_in,
                              void* d_out, int out_size, void* d_ws, size_t ws_size,
                              hipStream_t stream) {
    const float* x = (const float*)d_in[0];
    const float* w1 = (const float*)d_in[1];
    const float* b1 = (const float*)d_in[2];
    const float* w_score = (const float*)d_in[3];
    const float* b_score = (const float*)d_in[4];
    const float* w_loc = (const float*)d_in[5];
    const float* b_loc = (const float*)d_in[6];
    const int* img_h = (const int*)d_in[7];
    const int* img_w = (const int*)d_in[8];

    float* out = (float*)d_out;
    float* out_loc = out;                 // 4*22500*4 = 360000
    float* out_score = out + 360000;      // 4*22500*2 = 180000
    float* out_rois = out + 540000;       // 4*300*4   = 4800
    float* out_rind = out + 544800;       // 4*300     = 1200
    float* out_anchor = out + 546000;     // 22500*4   = 90000

    char* wsb = (char*)d_ws;
    double* inter64 = (double*)(wsb + 0);               // 10,240,000 (1 batch)
    double* loc64   = (double*)(wsb + 10240000);        //  2,880,000
    double* score64 = (double*)(wsb + 13120000);        //  1,440,000
    double* fg64    = (double*)(wsb + 14560000);        //    720,000
    double* boxes64 = (double*)(wsb + 15280000);        //  2,880,000
    u64*    keys    = (u64*)   (wsb + 18160000);        //    720,000
    double* sbox64  = (double*)(wsb + 18880000);        //    768,000
    int*    sval    = (int*)   (wsb + 19648000);        //     96,000

    hipLaunchKernelGGL(anchor_kernel, dim3(88), dim3(256), 0, stream, out_anchor);
    for (int n = 0; n < NB; ++n) {
        hipLaunchKernelGGL(conv3_kernel_f64, dim3(49, 8), dim3(256), 0, stream,
                           x, w1, b1, inter64, n);
        hipLaunchKernelGGL(heads_kernel_f64, dim3(20), dim3(256), 0, stream,
                           inter64, w_loc, b_loc, w_score, b_score,
                           loc64, score64, out_loc, out_score, n);
    }
    hipLaunchKernelGGL(fg_kernel_f64, dim3((NB * RR + 255) / 256), dim3(256), 0, stream,
                       score64, fg64);
    hipLaunchKernelGGL(box_kernel_f64, dim3((NB * RR + 255) / 256), dim3(256), 0, stream,
                       loc64, out_anchor, fg64, img_h, img_w, boxes64, keys);
    hipLaunchKernelGGL(select_kernel, dim3(4), dim3(1024), 0, stream, keys, boxes64, sbox64, sval);
    hipLaunchKernelGGL(nms_kernel_f64, dim3(4), dim3(1024), 0, stream, sbox64, sval, out_rois, out_rind);
}

// Round 3
// 3153.060 us; speedup vs baseline: 1.2763x; 1.2763x over previous
//
#include <hip/hip_runtime.h>
#include <stdint.h>
#include <math.h>

#define NB 4
#define CIN 512
#define CMID 512
#define HH 50
#define WW 50
#define NPIX 2500
#define AA 9
#define RR 22500
#define PB 6000
#define PA 300
#define LOCCH 36
#define SCORECH 18
#define HEADCH 54
#define CI_T 8

typedef unsigned long long u64;

// ---------------- anchors ----------------
__global__ void anchor_kernel(float* __restrict__ out4) {
    int r = blockIdx.x * 256 + threadIdx.x;
    if (r >= RR) return;
    int a = r % AA;
    int p = r / AA;
    int gy = p / WW, gx = p % WW;
    int ri = a / 3, si = a % 3;
    const double ratios[3] = {0.5, 1.0, 2.0};
    const double scales[3] = {8.0, 16.0, 32.0};
    double h = 16.0 * sqrt(ratios[ri]) * scales[si];
    double w = 16.0 * sqrt(1.0 / ratios[ri]) * scales[si];
    float by1 = (float)(8.0 - h * 0.5);
    float bx1 = (float)(8.0 - w * 0.5);
    float by2 = (float)(8.0 + h * 0.5);
    float bx2 = (float)(8.0 + w * 0.5);
    float sy = (float)(gy * 16), sx = (float)(gx * 16);
    float* o = out4 + (size_t)r * 4;
    o[0] = by1 + sy; o[1] = bx1 + sx; o[2] = by2 + sy; o[3] = bx2 + sx;
}

// ---------------- 3x3 conv + bias + relu, f64 accumulate ----------------
// grid (49, 8, nb), block 256. 64 couts x 8x8 px, 4x4/thread, ci-chunk 8.
// LDS holds f64 operands (converted once at staging); reads are double2.
__global__ __launch_bounds__(256) void conv3_f64_v2(
    const float* __restrict__ x, const float* __restrict__ w1,
    const float* __restrict__ b1, double* __restrict__ inter, int nbase) {
    __shared__ double xs[CI_T][10][10];       // 6400 B
    __shared__ double wsd[CI_T * 9][66];      // 38016 B (row 528 B, 16B aligned)

    int tile = blockIdx.x;
    int ty = tile / 7, tx = tile % 7;
    int co0 = blockIdx.y * 64;
    int bz = blockIdx.z;
    int n = nbase + bz;
    int tid = threadIdx.x;
    int tm = tid & 15;            // cout-quad id
    int tp = tid >> 4;            // pixel-quad id
    int pyt = tp >> 1;            // row 0..7
    int px0 = (tp & 1) * 4;       // col 0 or 4
    int gy0 = ty * 8, gx0 = tx * 8;
    const float* xb = x + (size_t)n * CIN * NPIX;
    double* ib = inter + (size_t)bz * CMID * NPIX;

    double acc[4][4] = {};

    for (int cc = 0; cc < CIN; cc += CI_T) {
        // stage x halo (8ci x 10x10), convert to f64 once
        for (int e = tid; e < CI_T * 100; e += 256) {
            int col = e % 10;
            int row = (e / 10) % 10;
            int ci = e / 100;
            int gy = gy0 - 1 + row, gx = gx0 - 1 + col;
            float v = 0.f;
            if (gy >= 0 && gy < HH && gx >= 0 && gx < WW)
                v = xb[(size_t)(cc + ci) * NPIX + gy * WW + gx];
            xs[ci][row][col] = (double)v;
        }
        // stage weights (64co x 72q), coalesced global, convert once
        for (int e = tid; e < 64 * 72; e += 256) {
            int m = e / 72;
            int q = e % 72;
            wsd[q][m] = (double)w1[((size_t)(co0 + m) * CIN + cc) * 9 + q];
        }
        __syncthreads();

        for (int ci = 0; ci < CI_T; ++ci) {
            #pragma unroll
            for (int ky = 0; ky < 3; ++ky) {
                double xa[6];
                const double* xrow = &xs[ci][pyt + ky][px0];
                *(double2*)&xa[0] = *(const double2*)&xrow[0];
                *(double2*)&xa[2] = *(const double2*)&xrow[2];
                *(double2*)&xa[4] = *(const double2*)&xrow[4];
                #pragma unroll
                for (int kx = 0; kx < 3; ++kx) {
                    const double* wr = &wsd[ci * 9 + ky * 3 + kx][tm * 4];
                    double2 wa = *(const double2*)&wr[0];
                    double2 wb = *(const double2*)&wr[2];
                    #pragma unroll
                    for (int j = 0; j < 4; ++j) {
                        double xv = xa[kx + j];
                        acc[0][j] = fma(wa.x, xv, acc[0][j]);
                        acc[1][j] = fma(wa.y, xv, acc[1][j]);
                        acc[2][j] = fma(wb.x, xv, acc[2][j]);
                        acc[3][j] = fma(wb.y, xv, acc[3][j]);
                    }
                }
            }
        }
        __syncthreads();
    }

    int gy = gy0 + pyt;
    #pragma unroll
    for (int i = 0; i < 4; ++i) {
        int co = co0 + tm * 4 + i;
        double bias = (double)b1[co];
        #pragma unroll
        for (int j = 0; j < 4; ++j) {
            int gx = gx0 + px0 + j;
            if (gy < HH && gx < WW) {
                double v = fmax(acc[i][j] + bias, 0.0);
                ib[(size_t)co * NPIX + gy * WW + gx] = v;
            }
        }
    }
}

// ---------------- 1x1 heads, f64, batched over grid.y ----------------
#define HP 128
#define HCI 32
__global__ __launch_bounds__(256) void heads_kernel_f64(
    const double* __restrict__ inter,
    const float* __restrict__ w_loc, const float* __restrict__ b_loc,
    const float* __restrict__ w_score, const float* __restrict__ b_score,
    double* __restrict__ loc64, double* __restrict__ score64,
    float* __restrict__ out_loc, float* __restrict__ out_score, int nbase) {
    __shared__ double xsh[HCI][HP];
    __shared__ double wsh[HEADCH][HCI];
    int bz = blockIdx.y;
    int n = nbase + bz;
    const double* ib = inter + (size_t)bz * CMID * NPIX;
    int p0 = blockIdx.x * HP;
    int tid = threadIdx.x;
    int pl = tid % HP;
    int g = tid / HP;
    double acc[27] = {};

    for (int cc = 0; cc < CMID; cc += HCI) {
        for (int e = tid; e < HCI * HP; e += 256) {
            int p = e % HP;
            int ci = e / HP;
            int gp = p0 + p;
            xsh[ci][p] = (gp < NPIX) ? ib[(size_t)(cc + ci) * NPIX + gp] : 0.0;
        }
        for (int e = tid; e < HEADCH * HCI; e += 256) {
            int ci = e % HCI;
            int u = e / HCI;
            float wv = (u < LOCCH) ? w_loc[(size_t)u * CMID + cc + ci]
                                   : w_score[(size_t)(u - LOCCH) * CMID + cc + ci];
            wsh[u][ci] = (double)wv;
        }
        __syncthreads();
        for (int ci = 0; ci < HCI; ++ci) {
            double xv = xsh[ci][pl];
            #pragma unroll
            for (int o = 0; o < 27; ++o)
                acc[o] = fma(wsh[g * 27 + o][ci], xv, acc[o]);
        }
        __syncthreads();
    }

    int gp = p0 + pl;
    if (gp < NPIX) {
        #pragma unroll
        for (int o = 0; o < 27; ++o) {
            int u = g * 27 + o;
            if (u < LOCCH) {
                double v = acc[o] + (double)b_loc[u];
                loc64[(size_t)n * RR * 4 + (size_t)gp * 36 + u] = v;
                out_loc[(size_t)n * RR * 4 + (size_t)gp * 36 + u] = (float)v;
            } else {
                int us = u - LOCCH;
                double v = acc[o] + (double)b_score[us];
                score64[(size_t)n * RR * 2 + (size_t)gp * 18 + us] = v;
                out_score[(size_t)n * RR * 2 + (size_t)gp * 18 + us] = (float)v;
            }
        }
    }
}

// ---------------- decode boxes + softmax-fg + keys, f64 ----------------
__global__ void box_kernel_f64(const double* __restrict__ loc64,
                               const double* __restrict__ score64,
                               const float* __restrict__ anchor,
                               const int* __restrict__ imh_p, const int* __restrict__ imw_p,
                               double* __restrict__ boxes, u64* __restrict__ keys) {
    int idx = blockIdx.x * 256 + threadIdx.x;
    if (idx >= NB * RR) return;
    int r = idx % RR;
    const double* l = loc64 + (size_t)idx * 4;
    double a0 = (double)anchor[(size_t)r * 4 + 0];
    double a1 = (double)anchor[(size_t)r * 4 + 1];
    double a2 = (double)anchor[(size_t)r * 4 + 2];
    double a3 = (double)anchor[(size_t)r * 4 + 3];
    double ah = a2 - a0, aw = a3 - a1;
    double acy = a0 + 0.5 * ah, acx = a1 + 0.5 * aw;
    double cy = l[0] * ah + acy, cx = l[1] * aw + acx;
    double h = exp(l[2]) * ah, w = exp(l[3]) * aw;
    double imh = (double)imh_p[0], imw = (double)imw_p[0];
    double y1 = fmin(fmax(cy - 0.5 * h, 0.0), imh);
    double x1 = fmin(fmax(cx - 0.5 * w, 0.0), imw);
    double y2 = fmin(fmax(cy + 0.5 * h, 0.0), imh);
    double x2 = fmin(fmax(cx + 0.5 * w, 0.0), imw);
    bool valid = ((y2 - y1) >= 16.0) && ((x2 - x1) >= 16.0);
    double* b = boxes + (size_t)idx * 4;
    b[0] = y1; b[1] = x1; b[2] = y2; b[3] = x2;
    // softmax fg (fused)
    double s0 = score64[(size_t)idx * 2];
    double s1 = score64[(size_t)idx * 2 + 1];
    double m = fmax(s0, s1);
    double e0 = exp(s0 - m), e1 = exp(s1 - m);
    double sc = valid ? (e1 / (e0 + e1)) : -__builtin_inf();
    u64 bits = (u64)__double_as_longlong(sc);
    u64 t = (bits >> 63) ? ~bits : (bits | 0x8000000000000000ull);
    keys[idx] = (t & 0xFFFFFFFFFFFF8000ull) | (u64)(32767 - r);
}

// ---------------- top-6000 select + full sort (per batch) ----------------
__global__ __launch_bounds__(1024) void select_kernel(
    const u64* __restrict__ keys, const double* __restrict__ boxes,
    double* __restrict__ sbox, int* __restrict__ sval) {
    __shared__ unsigned int hist[256];
    __shared__ u64 cand[8192];
    __shared__ unsigned int s_sel, s_base, s_cnt;
    int n = blockIdx.x;
    int tid = threadIdx.x;
    const u64* k = keys + (size_t)n * RR;

    u64 prefix = 0;
    unsigned int base = 0;
    for (int round = 0; round < 3; ++round) {
        if (tid < 256) hist[tid] = 0;
        __syncthreads();
        int shift_match = 64 - 8 * round;
        int shift_bin = 56 - 8 * round;
        for (int r = tid; r < RR; r += 1024) {
            u64 kv = k[r];
            bool match = (round == 0) || ((kv >> shift_match) == prefix);
            if (match) atomicAdd(&hist[(unsigned int)((kv >> shift_bin) & 0xFF)], 1u);
        }
        __syncthreads();
        if (tid == 0) {
            unsigned int c = base;
            int sel = 0;
            for (int v = 255; v >= 0; --v) {
                if (c + hist[v] >= PB) { sel = v; break; }
                c += hist[v];
            }
            s_sel = (unsigned int)sel;
            s_base = c;
        }
        __syncthreads();
        prefix = (prefix << 8) | (u64)s_sel;
        base = s_base;
        __syncthreads();
    }

    if (tid == 0) s_cnt = 0;
    __syncthreads();
    for (int r = tid; r < RR; r += 1024) {
        u64 kv = k[r];
        if ((kv >> 40) >= prefix) {
            unsigned int pos = atomicAdd(&s_cnt, 1u);
            if (pos < 8192u) cand[pos] = kv;
        }
    }
    __syncthreads();
    unsigned int cnt = s_cnt;
    if (cnt > 8192u) cnt = 8192u;
    for (unsigned int i = cnt + tid; i < 8192u; i += 1024u) cand[i] = 0ull;
    __syncthreads();

    for (unsigned int kk = 2; kk <= 8192; kk <<= 1) {
        for (unsigned int j = kk >> 1; j > 0; j >>= 1) {
            for (unsigned int t = tid; t < 4096; t += 1024) {
                unsigned int i = ((t & ~(j - 1)) << 1) | (t & (j - 1));
                unsigned int l = i | j;
                u64 a = cand[i], b = cand[l];
                bool desc = ((i & kk) == 0);
                if ((a < b) == desc) { cand[i] = b; cand[l] = a; }
            }
            __syncthreads();
        }
    }

    for (int s = tid; s < PB; s += 1024) {
        u64 kv = cand[s];
        int valid = (int)(kv >> 63);
        double b0 = 0.0, b1 = 0.0, b2 = 0.0, b3 = 0.0;
        if (valid) {
            int r = 32767 - (int)(kv & 0x7FFFull);
            const double* bp = boxes + ((size_t)n * RR + r) * 4;
            b0 = bp[0]; b1 = bp[1]; b2 = bp[2]; b3 = bp[3];
        }
        double* sp = sbox + ((size_t)n * PB + s) * 4;
        sp[0] = b0; sp[1] = b1; sp[2] = b2; sp[3] = b3;
        sval[n * PB + s] = valid;
    }
}

// ---------------- greedy NMS (f64 IoU), early-exit at 300 kept ----------------
__global__ __launch_bounds__(1024) void nms_kernel_f64(
    const double* __restrict__ sbox, const int* __restrict__ sval,
    float* __restrict__ rois, float* __restrict__ rind) {
    __shared__ unsigned int keepw[188];
    __shared__ double bi[4];
    int n = blockIdx.x;
    int tid = threadIdx.x;

    double by1[6], bx1[6], by2[6], bx2[6];
    bool kp[6];
    if (tid < 188) keepw[tid] = 0u;
    __syncthreads();
    #pragma unroll
    for (int c = 0; c < 6; ++c) {
        int j = tid + c * 1024;
        bool v = false;
        double a0 = 0, a1 = 0, a2 = 0, a3 = 0;
        if (j < PB) {
            const double* bp = sbox + ((size_t)n * PB + j) * 4;
            a0 = bp[0]; a1 = bp[1]; a2 = bp[2]; a3 = bp[3];
            v = sval[n * PB + j] != 0;
        }
        by1[c] = a0; bx1[c] = a1; by2[c] = a2; bx2[c] = a3;
        kp[c] = v;
        if (v) atomicOr(&keepw[j >> 5], 1u << (j & 31));
    }
    __syncthreads();

    int kc = 0;
    for (int i = 0; i < PB; ++i) {
        bool ki = (keepw[i >> 5] >> (i & 31)) & 1u;
        if (!ki) continue;
        int owner = i & 1023;
        int slot = i >> 10;
        if (tid == owner) {
            float* rp = rois + ((size_t)n * PA + kc) * 4;
            rp[0] = (float)by1[slot]; rp[1] = (float)bx1[slot];
            rp[2] = (float)by2[slot]; rp[3] = (float)bx2[slot];
            bi[0] = by1[slot]; bi[1] = bx1[slot]; bi[2] = by2[slot]; bi[3] = bx2[slot];
        }
        ++kc;
        if (kc >= PA) break;
        __syncthreads();
        double yi1 = bi[0], xi1 = bi[1], yi2 = bi[2], xi2 = bi[3];
        double ai = (yi2 - yi1) * (xi2 - xi1);
        #pragma unroll
        for (int c = 0; c < 6; ++c) {
            int j = tid + c * 1024;
            if (j > i && kp[c]) {
                double ty = fmax(yi1, by1[c]);
                double tx = fmax(xi1, bx1[c]);
                double byy = fmin(yi2, by2[c]);
                double bxx = fmin(xi2, bx2[c]);
                double ih = fmax(byy - ty, 0.0);
                double iw = fmax(bxx - tx, 0.0);
                double inter = ih * iw;
                double aj = (by2[c] - by1[c]) * (bx2[c] - bx1[c]);
                double iou = inter / (ai + aj - inter + 1e-9);
                if (iou > 0.7) {
                    kp[c] = false;
                    atomicAnd(&keepw[j >> 5], ~(1u << (j & 31)));
                }
            }
        }
        __syncthreads();
    }
    __syncthreads();

    for (int p = kc + tid; p < PA; p += 1024) {
        float* rp = rois + ((size_t)n * PA + p) * 4;
        rp[0] = 0.f; rp[1] = 0.f; rp[2] = 0.f; rp[3] = 0.f;
    }
    for (int p = tid; p < PA; p += 1024)
        rind[n * PA + p] = (float)n;
}

// ---------------- launch ----------------
extern "C" void kernel_launch(void* const* d_in, const int* in_sizes, int n_in,
                              void* d_out, int out_size, void* d_ws, size_t ws_size,
                              hipStream_t stream) {
    const float* x = (const float*)d_in[0];
    const float* w1 = (const float*)d_in[1];
    const float* b1 = (const float*)d_in[2];
    const float* w_score = (const float*)d_in[3];
    const float* b_score = (const float*)d_in[4];
    const float* w_loc = (const float*)d_in[5];
    const float* b_loc = (const float*)d_in[6];
    const int* img_h = (const int*)d_in[7];
    const int* img_w = (const int*)d_in[8];

    float* out = (float*)d_out;
    float* out_loc = out;                 // 4*22500*4
    float* out_score = out + 360000;      // 4*22500*2
    float* out_rois = out + 540000;       // 4*300*4
    float* out_rind = out + 544800;       // 4*300
    float* out_anchor = out + 546000;     // 22500*4

    // ws layout: batched needs ~49.75 MB (inter for 4 batches); else serialize conv.
    const size_t interB_batched = (size_t)NB * CMID * NPIX * 8;   // 40,960,000
    const size_t interB_serial = (size_t)CMID * NPIX * 8;         // 10,240,000
    const size_t restB = 2880000 + 1440000 + 2880000 + 720000 + 768000 + 96000;
    bool batched = ws_size >= interB_batched + restB;

    char* p = (char*)d_ws;
    double* inter64 = (double*)p; p += batched ? interB_batched : interB_serial;
    double* loc64   = (double*)p; p += 2880000;
    double* score64 = (double*)p; p += 1440000;
    double* boxes64 = (double*)p; p += 2880000;
    u64*    keys    = (u64*)p;    p += 720000;
    double* sbox64  = (double*)p; p += 768000;
    int*    sval    = (int*)p;

    hipLaunchKernelGGL(anchor_kernel, dim3(88), dim3(256), 0, stream, out_anchor);
    if (batched) {
        hipLaunchKernelGGL(conv3_f64_v2, dim3(49, 8, NB), dim3(256), 0, stream,
                           x, w1, b1, inter64, 0);
        hipLaunchKernelGGL(heads_kernel_f64, dim3(20, NB), dim3(256), 0, stream,
                           inter64, w_loc, b_loc, w_score, b_score,
                           loc64, score64, out_loc, out_score, 0);
    } else {
        for (int n = 0; n < NB; ++n) {
            hipLaunchKernelGGL(conv3_f64_v2, dim3(49, 8, 1), dim3(256), 0, stream,
                               x, w1, b1, inter64, n);
            hipLaunchKernelGGL(heads_kernel_f64, dim3(20, 1), dim3(256), 0, stream,
                               inter64, w_loc, b_loc, w_score, b_score,
                               loc64, score64, out_loc, out_score, n);
        }
    }
    hipLaunchKernelGGL(box_kernel_f64, dim3((NB * RR + 255) / 256), dim3(256), 0, stream,
                       loc64, score64, out_anchor, img_h, img_w, boxes64, keys);
    hipLaunchKernelGGL(select_kernel, dim3(4), dim3(1024), 0, stream, keys, boxes64, sbox64, sval);
    hipLaunchKernelGGL(nms_kernel_f64, dim3(4), dim3(1024), 0, stream, sbox64, sval, out_rois, out_rind);
}

// Round 5
// 2658.137 us; speedup vs baseline: 1.5140x; 1.1862x over previous
//
#include <hip/hip_runtime.h>
#include <stdint.h>
#include <math.h>

#define NB 4
#define CIN 512
#define CMID 512
#define HH 50
#define WW 50
#define NPIX 2500
#define AA 9
#define RR 22500
#define PB 6000
#define PA 300
#define LOCCH 36
#define SCORECH 18
#define HEADCH 54
#define CI_T 8

typedef unsigned long long u64;

// ---------------- anchors ----------------
__global__ void anchor_kernel(float* __restrict__ out4) {
    int r = blockIdx.x * 256 + threadIdx.x;
    if (r >= RR) return;
    int a = r % AA;
    int p = r / AA;
    int gy = p / WW, gx = p % WW;
    int ri = a / 3, si = a % 3;
    const double ratios[3] = {0.5, 1.0, 2.0};
    const double scales[3] = {8.0, 16.0, 32.0};
    double h = 16.0 * sqrt(ratios[ri]) * scales[si];
    double w = 16.0 * sqrt(1.0 / ratios[ri]) * scales[si];
    float by1 = (float)(8.0 - h * 0.5);
    float bx1 = (float)(8.0 - w * 0.5);
    float by2 = (float)(8.0 + h * 0.5);
    float bx2 = (float)(8.0 + w * 0.5);
    float sy = (float)(gy * 16), sx = (float)(gx * 16);
    float* o = out4 + (size_t)r * 4;
    o[0] = by1 + sy; o[1] = bx1 + sx; o[2] = by2 + sy; o[3] = bx2 + sx;
}

// ---------------- 3x3 conv + bias + relu, f64 accumulate ----------------
// grid (49, 8, nb), block 256. 64 couts x 8x8 px, 4x4/thread, ci-chunk 8.
// x staged as f64 (converted once); weights staged as f32 (exact cvt at use).
// FMA sequence identical to round-3 kernel -> bit-identical output.
__global__ __launch_bounds__(256) void conv3_f64_v3(
    const float* __restrict__ x, const float* __restrict__ w1,
    const float* __restrict__ b1, double* __restrict__ inter, int nbase) {
    __shared__ __align__(16) double xs[CI_T][10][10];   // 6400 B
    __shared__ __align__(16) float wsf[CI_T * 9][68];   // 19584 B, row 272B (16B mult)

    int tile = blockIdx.x;
    int ty = tile / 7, tx = tile % 7;
    int co0 = blockIdx.y * 64;
    int bz = blockIdx.z;
    int n = nbase + bz;
    int tid = threadIdx.x;
    int tm = tid & 15;            // cout-quad id
    int tp = tid >> 4;            // pixel-quad id
    int pyt = tp >> 1;            // row 0..7
    int px0 = (tp & 1) * 4;       // col 0 or 4
    int gy0 = ty * 8, gx0 = tx * 8;
    const float* xb = x + (size_t)n * CIN * NPIX;
    double* ib = inter + (size_t)bz * CMID * NPIX;

    double acc[4][4] = {};

    for (int cc = 0; cc < CIN; cc += CI_T) {
        // stage x halo (8ci x 10x10), convert to f64 once
        for (int e = tid; e < CI_T * 100; e += 256) {
            int ci = e / 100, rc = e % 100;
            int row = rc / 10, col = rc % 10;
            int gy = gy0 - 1 + row, gx = gx0 - 1 + col;
            float v = 0.f;
            if (gy >= 0 && gy < HH && gx >= 0 && gx < WW)
                v = xb[(size_t)(cc + ci) * NPIX + gy * WW + gx];
            xs[ci][row][col] = (double)v;
        }
        // stage weights as f32 (64co x 72q), coalesced global
        for (int e = tid; e < 64 * 72; e += 256) {
            int m = e / 72, q = e % 72;
            wsf[q][m] = w1[((size_t)(co0 + m) * CIN + cc) * 9 + q];
        }
        __syncthreads();

        for (int ci = 0; ci < CI_T; ++ci) {
            #pragma unroll
            for (int ky = 0; ky < 3; ++ky) {
                double xa[6];
                const double* xrow = &xs[ci][pyt + ky][px0];
                *(double2*)&xa[0] = *(const double2*)&xrow[0];
                *(double2*)&xa[2] = *(const double2*)&xrow[2];
                *(double2*)&xa[4] = *(const double2*)&xrow[4];
                #pragma unroll
                for (int kx = 0; kx < 3; ++kx) {
                    float4 wf = *(const float4*)&wsf[ci * 9 + ky * 3 + kx][tm * 4];
                    double w0 = (double)wf.x, w1v = (double)wf.y;
                    double w2 = (double)wf.z, w3 = (double)wf.w;
                    #pragma unroll
                    for (int j = 0; j < 4; ++j) {
                        double xv = xa[kx + j];
                        acc[0][j] = fma(w0, xv, acc[0][j]);
                        acc[1][j] = fma(w1v, xv, acc[1][j]);
                        acc[2][j] = fma(w2, xv, acc[2][j]);
                        acc[3][j] = fma(w3, xv, acc[3][j]);
                    }
                }
            }
        }
        __syncthreads();
    }

    int gy = gy0 + pyt;
    #pragma unroll
    for (int i = 0; i < 4; ++i) {
        int co = co0 + tm * 4 + i;
        double bias = (double)b1[co];
        #pragma unroll
        for (int j = 0; j < 4; ++j) {
            int gx = gx0 + px0 + j;
            if (gy < HH && gx < WW) {
                double v = fmax(acc[i][j] + bias, 0.0);
                ib[(size_t)co * NPIX + gy * WW + gx] = v;
            }
        }
    }
}

// ---------------- 1x1 heads, f64, batched over grid.y ----------------
// block 128, HP=64 px/block -> grid (40, nb) = 160 blocks
#define HP 64
#define HCI 32
__global__ __launch_bounds__(128) void heads_kernel_f64(
    const double* __restrict__ inter,
    const float* __restrict__ w_loc, const float* __restrict__ b_loc,
    const float* __restrict__ w_score, const float* __restrict__ b_score,
    double* __restrict__ loc64, double* __restrict__ score64,
    float* __restrict__ out_loc, float* __restrict__ out_score, int nbase) {
    __shared__ double xsh[HCI][HP];
    __shared__ double wsh[HEADCH][HCI];
    int bz = blockIdx.y;
    int n = nbase + bz;
    const double* ib = inter + (size_t)bz * CMID * NPIX;
    int p0 = blockIdx.x * HP;
    int tid = threadIdx.x;
    int pl = tid & 63;
    int g = tid >> 6;     // 0..1, 27 channels each
    double acc[27] = {};

    for (int cc = 0; cc < CMID; cc += HCI) {
        for (int e = tid; e < HCI * HP; e += 128) {
            int p = e % HP;
            int ci = e / HP;
            int gp = p0 + p;
            xsh[ci][p] = (gp < NPIX) ? ib[(size_t)(cc + ci) * NPIX + gp] : 0.0;
        }
        for (int e = tid; e < HEADCH * HCI; e += 128) {
            int ci = e % HCI;
            int u = e / HCI;
            float wv = (u < LOCCH) ? w_loc[(size_t)u * CMID + cc + ci]
                                   : w_score[(size_t)(u - LOCCH) * CMID + cc + ci];
            wsh[u][ci] = (double)wv;
        }
        __syncthreads();
        for (int ci = 0; ci < HCI; ++ci) {
            double xv = xsh[ci][pl];
            #pragma unroll
            for (int o = 0; o < 27; ++o)
                acc[o] = fma(wsh[g * 27 + o][ci], xv, acc[o]);
        }
        __syncthreads();
    }

    int gp = p0 + pl;
    if (gp < NPIX) {
        #pragma unroll
        for (int o = 0; o < 27; ++o) {
            int u = g * 27 + o;
            if (u < LOCCH) {
                double v = acc[o] + (double)b_loc[u];
                loc64[(size_t)n * RR * 4 + (size_t)gp * 36 + u] = v;
                out_loc[(size_t)n * RR * 4 + (size_t)gp * 36 + u] = (float)v;
            } else {
                int us = u - LOCCH;
                double v = acc[o] + (double)b_score[us];
                score64[(size_t)n * RR * 2 + (size_t)gp * 18 + us] = v;
                out_score[(size_t)n * RR * 2 + (size_t)gp * 18 + us] = (float)v;
            }
        }
    }
}

// ---------------- decode boxes + softmax-fg + keys, f64 ----------------
__global__ void box_kernel_f64(const double* __restrict__ loc64,
                               const double* __restrict__ score64,
                               const float* __restrict__ anchor,
                               const int* __restrict__ imh_p, const int* __restrict__ imw_p,
                               double* __restrict__ boxes, u64* __restrict__ keys) {
    int idx = blockIdx.x * 256 + threadIdx.x;
    if (idx >= NB * RR) return;
    int r = idx % RR;
    const double* l = loc64 + (size_t)idx * 4;
    double a0 = (double)anchor[(size_t)r * 4 + 0];
    double a1 = (double)anchor[(size_t)r * 4 + 1];
    double a2 = (double)anchor[(size_t)r * 4 + 2];
    double a3 = (double)anchor[(size_t)r * 4 + 3];
    double ah = a2 - a0, aw = a3 - a1;
    double acy = a0 + 0.5 * ah, acx = a1 + 0.5 * aw;
    double cy = l[0] * ah + acy, cx = l[1] * aw + acx;
    double h = exp(l[2]) * ah, w = exp(l[3]) * aw;
    double imh = (double)imh_p[0], imw = (double)imw_p[0];
    double y1 = fmin(fmax(cy - 0.5 * h, 0.0), imh);
    double x1 = fmin(fmax(cx - 0.5 * w, 0.0), imw);
    double y2 = fmin(fmax(cy + 0.5 * h, 0.0), imh);
    double x2 = fmin(fmax(cx + 0.5 * w, 0.0), imw);
    bool valid = ((y2 - y1) >= 16.0) && ((x2 - x1) >= 16.0);
    double* b = boxes + (size_t)idx * 4;
    b[0] = y1; b[1] = x1; b[2] = y2; b[3] = x2;
    double s0 = score64[(size_t)idx * 2];
    double s1 = score64[(size_t)idx * 2 + 1];
    double m = fmax(s0, s1);
    double e0 = exp(s0 - m), e1 = exp(s1 - m);
    double sc = valid ? (e1 / (e0 + e1)) : -__builtin_inf();
    u64 bits = (u64)__double_as_longlong(sc);
    u64 t = (bits >> 63) ? ~bits : (bits | 0x8000000000000000ull);
    keys[idx] = (t & 0xFFFFFFFFFFFF8000ull) | (u64)(32767 - r);
}

// ---------------- top-6000 select + full sort (per batch) ----------------
__global__ __launch_bounds__(1024) void select_kernel(
    const u64* __restrict__ keys, const double* __restrict__ boxes,
    double* __restrict__ sbox, int* __restrict__ sval) {
    __shared__ unsigned int hist[256];
    __shared__ u64 cand[8192];
    __shared__ unsigned int s_sel, s_base, s_cnt;
    int n = blockIdx.x;
    int tid = threadIdx.x;
    const u64* k = keys + (size_t)n * RR;

    u64 prefix = 0;
    unsigned int base = 0;
    for (int round = 0; round < 3; ++round) {
        if (tid < 256) hist[tid] = 0;
        __syncthreads();
        int shift_match = 64 - 8 * round;
        int shift_bin = 56 - 8 * round;
        for (int r = tid; r < RR; r += 1024) {
            u64 kv = k[r];
            bool match = (round == 0) || ((kv >> shift_match) == prefix);
            if (match) atomicAdd(&hist[(unsigned int)((kv >> shift_bin) & 0xFF)], 1u);
        }
        __syncthreads();
        if (tid == 0) {
            unsigned int c = base;
            int sel = 0;
            for (int v = 255; v >= 0; --v) {
                if (c + hist[v] >= PB) { sel = v; break; }
                c += hist[v];
            }
            s_sel = (unsigned int)sel;
            s_base = c;
        }
        __syncthreads();
        prefix = (prefix << 8) | (u64)s_sel;
        base = s_base;
        __syncthreads();
    }

    if (tid == 0) s_cnt = 0;
    __syncthreads();
    for (int r = tid; r < RR; r += 1024) {
        u64 kv = k[r];
        if ((kv >> 40) >= prefix) {
            unsigned int pos = atomicAdd(&s_cnt, 1u);
            if (pos < 8192u) cand[pos] = kv;
        }
    }
    __syncthreads();
    unsigned int cnt = s_cnt;
    if (cnt > 8192u) cnt = 8192u;
    for (unsigned int i = cnt + tid; i < 8192u; i += 1024u) cand[i] = 0ull;
    __syncthreads();

    for (unsigned int kk = 2; kk <= 8192; kk <<= 1) {
        for (unsigned int j = kk >> 1; j > 0; j >>= 1) {
            for (unsigned int t = tid; t < 4096; t += 1024) {
                unsigned int i = ((t & ~(j - 1)) << 1) | (t & (j - 1));
                unsigned int l = i | j;
                u64 a = cand[i], b = cand[l];
                bool desc = ((i & kk) == 0);
                if ((a < b) == desc) { cand[i] = b; cand[l] = a; }
            }
            __syncthreads();
        }
    }

    for (int s = tid; s < PB; s += 1024) {
        u64 kv = cand[s];
        int valid = (int)(kv >> 63);
        double b0 = 0.0, b1 = 0.0, b2 = 0.0, b3 = 0.0;
        if (valid) {
            int r = 32767 - (int)(kv & 0x7FFFull);
            const double* bp = boxes + ((size_t)n * RR + r) * 4;
            b0 = bp[0]; b1 = bp[1]; b2 = bp[2]; b3 = bp[3];
        }
        double* sp = sbox + ((size_t)n * PB + s) * 4;
        sp[0] = b0; sp[1] = b1; sp[2] = b2; sp[3] = b3;
        sval[n * PB + s] = valid;
    }
}

// ---------------- greedy NMS (f64 IoU), early-exit at 300 kept ----------------
__global__ __launch_bounds__(1024) void nms_kernel_f64(
    const double* __restrict__ sbox, const int* __restrict__ sval,
    float* __restrict__ rois, float* __restrict__ rind) {
    __shared__ unsigned int keepw[188];
    __shared__ double bi[4];
    int n = blockIdx.x;
    int tid = threadIdx.x;

    double by1[6], bx1[6], by2[6], bx2[6];
    bool kp[6];
    if (tid < 188) keepw[tid] = 0u;
    __syncthreads();
    #pragma unroll
    for (int c = 0; c < 6; ++c) {
        int j = tid + c * 1024;
        bool v = false;
        double a0 = 0, a1 = 0, a2 = 0, a3 = 0;
        if (j < PB) {
            const double* bp = sbox + ((size_t)n * PB + j) * 4;
            a0 = bp[0]; a1 = bp[1]; a2 = bp[2]; a3 = bp[3];
            v = sval[n * PB + j] != 0;
        }
        by1[c] = a0; bx1[c] = a1; by2[c] = a2; bx2[c] = a3;
        kp[c] = v;
        if (v) atomicOr(&keepw[j >> 5], 1u << (j & 31));
    }
    __syncthreads();

    int kc = 0;
    for (int i = 0; i < PB; ++i) {
        bool ki = (keepw[i >> 5] >> (i & 31)) & 1u;
        if (!ki) continue;
        int owner = i & 1023;
        int slot = i >> 10;
        if (tid == owner) {
            float* rp = rois + ((size_t)n * PA + kc) * 4;
            rp[0] = (float)by1[slot]; rp[1] = (float)bx1[slot];
            rp[2] = (float)by2[slot]; rp[3] = (float)bx2[slot];
            bi[0] = by1[slot]; bi[1] = bx1[slot]; bi[2] = by2[slot]; bi[3] = bx2[slot];
        }
        ++kc;
        if (kc >= PA) break;
        __syncthreads();
        double yi1 = bi[0], xi1 = bi[1], yi2 = bi[2], xi2 = bi[3];
        double ai = (yi2 - yi1) * (xi2 - xi1);
        #pragma unroll
        for (int c = 0; c < 6; ++c) {
            int j = tid + c * 1024;
            if (j > i && kp[c]) {
                double ty = fmax(yi1, by1[c]);
                double tx = fmax(xi1, bx1[c]);
                double byy = fmin(yi2, by2[c]);
                double bxx = fmin(xi2, bx2[c]);
                double ih = fmax(byy - ty, 0.0);
                double iw = fmax(bxx - tx, 0.0);
                double inter = ih * iw;
                double aj = (by2[c] - by1[c]) * (bx2[c] - bx1[c]);
                double iou = inter / (ai + aj - inter + 1e-9);
                if (iou > 0.7) {
                    kp[c] = false;
                    atomicAnd(&keepw[j >> 5], ~(1u << (j & 31)));
                }
            }
        }
        __syncthreads();
    }
    __syncthreads();

    for (int p = kc + tid; p < PA; p += 1024) {
        float* rp = rois + ((size_t)n * PA + p) * 4;
        rp[0] = 0.f; rp[1] = 0.f; rp[2] = 0.f; rp[3] = 0.f;
    }
    for (int p = tid; p < PA; p += 1024)
        rind[n * PA + p] = (float)n;
}

// ---------------- launch ----------------
extern "C" void kernel_launch(void* const* d_in, const int* in_sizes, int n_in,
                              void* d_out, int out_size, void* d_ws, size_t ws_size,
                              hipStream_t stream) {
    const float* x = (const float*)d_in[0];
    const float* w1 = (const float*)d_in[1];
    const float* b1 = (const float*)d_in[2];
    const float* w_score = (const float*)d_in[3];
    const float* b_score = (const float*)d_in[4];
    const float* w_loc = (const float*)d_in[5];
    const float* b_loc = (const float*)d_in[6];
    const int* img_h = (const int*)d_in[7];
    const int* img_w = (const int*)d_in[8];

    float* out = (float*)d_out;
    float* out_loc = out;
    float* out_score = out + 360000;
    float* out_rois = out + 540000;
    float* out_rind = out + 544800;
    float* out_anchor = out + 546000;

    const size_t interB_batched = (size_t)NB * CMID * NPIX * 8;
    const size_t interB_serial = (size_t)CMID * NPIX * 8;
    const size_t restB = 2880000 + 1440000 + 2880000 + 720000 + 768000 + 96000;
    bool batched = ws_size >= interB_batched + restB;

    char* p = (char*)d_ws;
    double* inter64 = (double*)p; p += batched ? interB_batched : interB_serial;
    double* loc64   = (double*)p; p += 2880000;
    double* score64 = (double*)p; p += 1440000;
    double* boxes64 = (double*)p; p += 2880000;
    u64*    keys    = (u64*)p;    p += 720000;
    double* sbox64  = (double*)p; p += 768000;
    int*    sval    = (int*)p;

    hipLaunchKernelGGL(anchor_kernel, dim3(88), dim3(256), 0, stream, out_anchor);
    if (batched) {
        hipLaunchKernelGGL(conv3_f64_v3, dim3(49, 8, NB), dim3(256), 0, stream,
                           x, w1, b1, inter64, 0);
        hipLaunchKernelGGL(heads_kernel_f64, dim3(40, NB), dim3(128), 0, stream,
                           inter64, w_loc, b_loc, w_score, b_score,
                           loc64, score64, out_loc, out_score, 0);
    } else {
        for (int n = 0; n < NB; ++n) {
            hipLaunchKernelGGL(conv3_f64_v3, dim3(49, 8, 1), dim3(256), 0, stream,
                               x, w1, b1, inter64, n);
            hipLaunchKernelGGL(heads_kernel_f64, dim3(40, 1), dim3(128), 0, stream,
                               inter64, w_loc, b_loc, w_score, b_score,
                               loc64, score64, out_loc, out_score, n);
        }
    }
    hipLaunchKernelGGL(box_kernel_f64, dim3((NB * RR + 255) / 256), dim3(256), 0, stream,
                       loc64, score64, out_anchor, img_h, img_w, boxes64, keys);
    hipLaunchKernelGGL(select_kernel, dim3(4), dim3(1024), 0, stream, keys, boxes64, sbox64, sval);
    hipLaunchKernelGGL(nms_kernel_f64, dim3(4), dim3(1024), 0, stream, sbox64, sval, out_rois, out_rind);
}